// Round 1
// baseline (396.513 us; speedup 1.0000x reference)
//
#include <hip/hip_runtime.h>

#define NPOINTS 262144
#define SUMH 224
#define SUMW 221
#define NREG 500

// ---------- wave-level helpers (VALU-rate DPP reductions, readlane broadcast) ----------

__device__ __forceinline__ float rlane(float v, int l) {
  return __int_as_float(__builtin_amdgcn_readlane(__float_as_int(v), l));
}

template<int CTRL>
__device__ __forceinline__ float dpp_add(float x) {
  // old = 0, bound_ctrl=false -> out-of-bounds source lanes contribute 0
  return x + __int_as_float(__builtin_amdgcn_update_dpp(0, __float_as_int(x), CTRL, 0xF, 0xF, false));
}
template<int CTRL>
__device__ __forceinline__ float dpp_max(float x) {
  // old = x -> identity for max on invalid lanes
  return fmaxf(x, __int_as_float(__builtin_amdgcn_update_dpp(__float_as_int(x), __float_as_int(x), CTRL, 0xF, 0xF, false)));
}

// classic GCN 64-lane reduce: row_shr:1,2,4,8 then row_bcast:15, row_bcast:31 -> lane63
__device__ __forceinline__ float wave_sum(float x) {
  x = dpp_add<0x111>(x);
  x = dpp_add<0x112>(x);
  x = dpp_add<0x114>(x);
  x = dpp_add<0x118>(x);
  x = dpp_add<0x142>(x);
  x = dpp_add<0x143>(x);
  return rlane(x, 63);
}
__device__ __forceinline__ float wave_max(float x) {
  x = dpp_max<0x111>(x);
  x = dpp_max<0x112>(x);
  x = dpp_max<0x114>(x);
  x = dpp_max<0x118>(x);
  x = dpp_max<0x142>(x);
  x = dpp_max<0x143>(x);
  return rlane(x, 63);
}

// ---------- Kernel 1: per-region-of-interest tables ----------
// Layout in ws (per rix in [0,500), stride 224 floats):
//   Wh: half-widths 0.5*softmax(uw), level slots {0..127, 128..191, 192..223},
//       unused tail slots are exactly 0 (softmax of -inf), which zeroes seam terms later.
//   BL: bin locations per level: n values {0, c0, ..., c_{n-2}=1.0}

template<int NM1, int SRC, int DST, int NSLOT>
__device__ __forceinline__ void region_level(const float* __restrict__ wrow,
    float* __restrict__ wW, float* __restrict__ wB, int lane, float* lds)
{
  float v0 = (lane < NM1) ? wrow[SRC + lane] : -1e30f;
  float v1 = -1e30f;
  if constexpr (NSLOT == 128) {
    if (lane + 64 < NM1) v1 = wrow[SRC + lane + 64];
  }
  float m = wave_max(fmaxf(v0, v1));
  float e0 = __expf(v0 - m);                       // 0 for padded lanes
  float e1 = (NSLOT == 128) ? __expf(v1 - m) : 0.0f;
  float s = wave_sum(e0 + e1);
  float inv = 1.0f / s;
  if (lane < NSLOT) { wW[DST + lane] = 0.5f * e0 * inv; lds[lane] = e0; }
  if constexpr (NSLOT == 128) { wW[DST + lane + 64] = 0.5f * e1 * inv; lds[lane + 64] = e1; }
  __syncthreads();
  if (lane == 0) {
    wB[DST] = 0.0f;
    float run = 0.0f;
    for (int k = 0; k < NM1; ++k) {
      run += lds[k];
      wB[DST + 1 + k] = (k == NM1 - 1) ? 1.0f : run * inv;
    }
  }
  __syncthreads();
}

__global__ void __launch_bounds__(64) region_kernel(
    const int* __restrict__ roi, const float* __restrict__ wemb,
    float* __restrict__ wsW, float* __restrict__ wsB)
{
  __shared__ float lds[128];
  int rix = blockIdx.x;
  int lane = threadIdx.x;
  int greg = roi[rix];
  const float* wrow = wemb + (size_t)greg * SUMW;
  float* wW = wsW + (size_t)rix * SUMH;
  float* wB = wsB + (size_t)rix * SUMH;
  region_level<127,   0,   0, 128>(wrow, wW, wB, lane, lds);
  region_level< 63, 127, 128,  64>(wrow, wW, wB, lane, lds);
  region_level< 31, 190, 192,  32>(wrow, wW, wB, lane, lds);
}

// ---------- Kernel 2: one wave per point, lanes <-> columns ----------

template<int N, int OFF>
__device__ __forceinline__ void spline_level(float& xv, float& logdet,
    const float* __restrict__ U, const float* __restrict__ D,
    const float* __restrict__ Wt, const float* __restrict__ Bt, int lane)
{
  float area, part, hl, hr, inloc, inw;
  if constexpr (N == 128) {
    int k0 = lane, k1 = lane + 64;
    float bl0 = Bt[OFF + k0], bl1 = Bt[OFF + k1];
    float wh0 = Wt[OFF + k0], wh1 = Wt[OFF + k1];   // slot 127 is 0 -> lane63's t1 = 0
    float he0 = __expf(U[OFF + k0] + D[OFF + k0]);
    float he1 = __expf(U[OFF + k1] + D[OFF + k1]);
    float hn0 = __expf(U[OFF + k0 + 1] + D[OFF + k0 + 1]);  // he[k+1], redundant load handles seam
    float hn1 = __expf(U[OFF + k1 + 1] + D[OFF + k1 + 1]);  // k1+1 <= 128+64 < 224, finite junk * 0
    float t0 = (he0 + hn0) * wh0;
    float t1 = (he1 + hn1) * wh1;
    int cnt = __popcll(__ballot(bl0 < xv)) + __popcll(__ballot(bl1 < xv));
    int bi = min(max(cnt - 1, 0), N - 2);
    float p0 = (k0 < bi) ? t0 : 0.0f;
    float p1 = (k1 < bi) ? t1 : 0.0f;
    area = wave_sum(t0 + t1);
    part = wave_sum(p0 + p1);
    int bi1 = bi + 1;
    hl    = (bi  < 64) ? rlane(he0, bi)       : rlane(he1, (bi  - 64) & 63);
    hr    = (bi1 < 64) ? rlane(he0, bi1)      : rlane(he1, (bi1 - 64) & 63);
    inloc = (bi  < 64) ? rlane(bl0, bi)       : rlane(bl1, (bi  - 64) & 63);
    inw   = 2.0f * ((bi < 64) ? rlane(wh0, bi) : rlane(wh1, (bi - 64) & 63));
  } else {
    int k0 = (N == 32) ? min(lane, 31) : lane;      // lanes >=32 alias col 31; their wh=0
    float bl0 = Bt[OFF + k0];
    float wh0 = Wt[OFF + k0];
    float he0 = __expf(U[OFF + k0] + D[OFF + k0]);
    int in1 = min(OFF + k0 + 1, SUMH - 1);          // clamp row end (level 2, lane 31)
    float hn0 = __expf(U[in1] + D[in1]);
    float t0 = (he0 + hn0) * wh0;
    int cnt = __popcll(__ballot(bl0 < xv));         // N=32: lanes>=32 see BL=1.0, never < x<=1
    int bi = min(max(cnt - 1, 0), N - 2);
    float p0 = (k0 < bi) ? t0 : 0.0f;
    area = wave_sum(t0);
    part = wave_sum(p0);
    hl = rlane(he0, bi);
    hr = rlane(he0, bi + 1);
    inloc = rlane(bl0, bi);
    inw = 2.0f * rlane(wh0, bi);
  }
  float inv_area = __builtin_amdgcn_rcpf(area);
  float alpha = (xv - inloc) * __builtin_amdgcn_rcpf(inw);
  float dh = hr - hl;
  float o = ((0.5f * dh * alpha + hl) * alpha * inw + part) * inv_area;
  float v = alpha * dh + hl;
  // log(v/area) = (log2(v) - log2(area)) * ln2
  logdet += (__log2f(v) - __log2f(area)) * 0.69314718055994531f;
  xv = o;
}

__global__ void __launch_bounds__(256) spline_kernel(
    const float* __restrict__ x, const int* __restrict__ roi,
    const int* __restrict__ lix, const float* __restrict__ delta,
    const float* __restrict__ hemb,
    const float* __restrict__ wsW, const float* __restrict__ wsB,
    float* __restrict__ out)
{
  int wid = (int)((blockIdx.x * blockDim.x + threadIdx.x) >> 6);
  int lane = (int)(threadIdx.x & 63);
  if (wid >= NPOINTS) return;
  float xv = x[wid];                      // wave-uniform
  int r = lix[wid];
  int greg = roi[r];
  const float* U  = hemb  + (size_t)greg * SUMH;
  const float* D  = delta + (size_t)wid  * SUMH;
  const float* Wt = wsW   + (size_t)r    * SUMH;
  const float* Bt = wsB   + (size_t)r    * SUMH;
  float logdet = 0.0f;
  spline_level<128,   0>(xv, logdet, U, D, Wt, Bt, lane);
  spline_level< 64, 128>(xv, logdet, U, D, Wt, Bt, lane);
  spline_level< 32, 192>(xv, logdet, U, D, Wt, Bt, lane);
  if (lane == 0) {
    out[wid] = xv;
    out[NPOINTS + wid] = logdet;
  }
}

// ---------- launch ----------

extern "C" void kernel_launch(void* const* d_in, const int* in_sizes, int n_in,
                              void* d_out, int out_size, void* d_ws, size_t ws_size,
                              hipStream_t stream) {
  const float* x     = (const float*)d_in[0];
  const int*   roi   = (const int*)  d_in[1];
  const int*   lix   = (const int*)  d_in[2];
  const float* delta = (const float*)d_in[3];
  const float* hemb  = (const float*)d_in[4];
  const float* wemb  = (const float*)d_in[5];

  float* wsW = (float*)d_ws;                 // [500][224] half-widths (zero-padded)
  float* wsB = wsW + (size_t)NREG * SUMH;    // [500][224] bin locations

  region_kernel<<<NREG, 64, 0, stream>>>(roi, wemb, wsW, wsB);
  spline_kernel<<<NPOINTS / 4, 256, 0, stream>>>(x, roi, lix, delta, hemb, wsW, wsB, (float*)d_out);
}

// Round 2
// 388.966 us; speedup vs baseline: 1.0194x; 1.0194x over previous
//
#include <hip/hip_runtime.h>

#define NPOINTS 262144
#define SUMH 224
#define SUMW 221
#define NREG 500

// ---------- 64-lane wave reduce (region kernel only) ----------
__device__ __forceinline__ float rlane(float v, int l) {
  return __int_as_float(__builtin_amdgcn_readlane(__float_as_int(v), l));
}
template<int CTRL>
__device__ __forceinline__ float dpp_add(float x) {
  return x + __int_as_float(__builtin_amdgcn_update_dpp(0, __float_as_int(x), CTRL, 0xF, 0xF, false));
}
template<int CTRL>
__device__ __forceinline__ float dpp_max(float x) {
  return fmaxf(x, __int_as_float(__builtin_amdgcn_update_dpp(__float_as_int(x), __float_as_int(x), CTRL, 0xF, 0xF, false)));
}
__device__ __forceinline__ float wave_sum(float x) {
  x = dpp_add<0x111>(x); x = dpp_add<0x112>(x); x = dpp_add<0x114>(x);
  x = dpp_add<0x118>(x); x = dpp_add<0x142>(x); x = dpp_add<0x143>(x);
  return rlane(x, 63);
}
__device__ __forceinline__ float wave_max(float x) {
  x = dpp_max<0x111>(x); x = dpp_max<0x112>(x); x = dpp_max<0x114>(x);
  x = dpp_max<0x118>(x); x = dpp_max<0x142>(x); x = dpp_max<0x143>(x);
  return rlane(x, 63);
}

// ---------- 16-lane group butterfly (all lanes end with group total) ----------
// steps: xor1 (quad_perm[1,0,3,2]=0xB1), xor2 (quad_perm[2,3,0,1]=0x4E),
//        row_half_mirror (0x141), row_mirror (0x140) — stays inside DPP rows.
__device__ __forceinline__ float grp_sum(float x) {
  x += __int_as_float(__builtin_amdgcn_update_dpp(0, __float_as_int(x), 0xB1,  0xF, 0xF, true));
  x += __int_as_float(__builtin_amdgcn_update_dpp(0, __float_as_int(x), 0x4E,  0xF, 0xF, true));
  x += __int_as_float(__builtin_amdgcn_update_dpp(0, __float_as_int(x), 0x141, 0xF, 0xF, true));
  x += __int_as_float(__builtin_amdgcn_update_dpp(0, __float_as_int(x), 0x140, 0xF, 0xF, true));
  return x;
}
__device__ __forceinline__ int grp_sum_i(int x) {
  x += __builtin_amdgcn_update_dpp(0, x, 0xB1,  0xF, 0xF, true);
  x += __builtin_amdgcn_update_dpp(0, x, 0x4E,  0xF, 0xF, true);
  x += __builtin_amdgcn_update_dpp(0, x, 0x141, 0xF, 0xF, true);
  x += __builtin_amdgcn_update_dpp(0, x, 0x140, 0xF, 0xF, true);
  return x;
}

// ---------- Kernel 1: per-ROI tables ----------
// Per rix (stride SUMH floats), level slots {0..127, 128..191, 192..223}:
//   BL[j] = bin edge j (BL[0]=0, BL[NB-1]=1 exactly)
//   HW[j] = 0.5*w_j      (0 for j=NB-1)
//   HM[j] = 0.5*w_{j-1}  (0 for j=0)
// area = sum_j he_j*(HW_j+HM_j); cdf(bi) = sum_{j<=bi} he_j*(HW_j+HM_j) - he_bi*HW_bi

template<int M, int SRC, int DST, int NB>
__device__ __forceinline__ void region_level(const float* __restrict__ wrow,
    float* __restrict__ BL, float* __restrict__ HW, float* __restrict__ HM,
    int lane, float* lds)
{
  float v0 = (lane < M) ? wrow[SRC + lane] : -1e30f;
  float v1 = -1e30f;
  if constexpr (NB == 128) { if (lane + 64 < M) v1 = wrow[SRC + lane + 64]; }
  float m = wave_max(fmaxf(v0, v1));
  float e0 = __expf(v0 - m);                 // 0 for padded slots
  float e1 = (NB == 128) ? __expf(v1 - m) : 0.0f;
  float s = wave_sum(e0 + e1);
  float inv = 1.0f / s;
  if (lane < NB) lds[lane] = e0;
  if constexpr (NB == 128) lds[lane + 64] = e1;
  __syncthreads();
  if (lane < NB) {
    HW[DST + lane] = 0.5f * e0 * inv;
    HM[DST + lane] = (lane == 0) ? 0.0f : 0.5f * lds[lane - 1] * inv;
  }
  if constexpr (NB == 128) {
    HW[DST + lane + 64] = 0.5f * e1 * inv;
    HM[DST + lane + 64] = 0.5f * lds[lane + 63] * inv;
  }
  if (lane == 0) {
    BL[DST] = 0.0f;
    float run = 0.0f;
    for (int k = 0; k < M; ++k) {
      run += lds[k];
      BL[DST + 1 + k] = (k == M - 1) ? 1.0f : run * inv;
    }
  }
  __syncthreads();
}

__global__ void __launch_bounds__(64) region_kernel(
    const int* __restrict__ roi, const float* __restrict__ wemb,
    float* __restrict__ wsBL, float* __restrict__ wsHW, float* __restrict__ wsHM)
{
  __shared__ float lds[128];
  int rix = blockIdx.x;
  int lane = threadIdx.x;
  int greg = roi[rix];
  const float* wrow = wemb + (size_t)greg * SUMW;
  float* BL = wsBL + (size_t)rix * SUMH;
  float* HW = wsHW + (size_t)rix * SUMH;
  float* HM = wsHM + (size_t)rix * SUMH;
  region_level<127,   0,   0, 128>(wrow, BL, HW, HM, lane, lds);
  region_level< 63, 127, 128,  64>(wrow, BL, HW, HM, lane, lds);
  region_level< 31, 190, 192,  32>(wrow, BL, HW, HM, lane, lds);
}

// ---------- Kernel 2: 4 points per wave, 16-lane groups, lanes <-> columns ----------

template<int NB, int OFF, int C>
__device__ __forceinline__ void level(float& xv, float& logdet,
    const float* __restrict__ U, const float* __restrict__ D,
    const float* __restrict__ BLt, const float* __restrict__ HWt,
    const float* __restrict__ HMt, int s)
{
  float u[C], d[C], bl[C], hw[C], hm[C];
  if constexpr (C >= 4) {
#pragma unroll
    for (int v = 0; v < C / 4; ++v) {
      int c0 = OFF + (s * (C / 4) + v) * 4;
      float4 a = *(const float4*)(U   + c0);
      float4 b = *(const float4*)(D   + c0);
      float4 e = *(const float4*)(BLt + c0);
      float4 f = *(const float4*)(HWt + c0);
      float4 g = *(const float4*)(HMt + c0);
      u[4*v+0]=a.x; u[4*v+1]=a.y; u[4*v+2]=a.z; u[4*v+3]=a.w;
      d[4*v+0]=b.x; d[4*v+1]=b.y; d[4*v+2]=b.z; d[4*v+3]=b.w;
      bl[4*v+0]=e.x; bl[4*v+1]=e.y; bl[4*v+2]=e.z; bl[4*v+3]=e.w;
      hw[4*v+0]=f.x; hw[4*v+1]=f.y; hw[4*v+2]=f.z; hw[4*v+3]=f.w;
      hm[4*v+0]=g.x; hm[4*v+1]=g.y; hm[4*v+2]=g.z; hm[4*v+3]=g.w;
    }
  } else {
    int c0 = OFF + s * 2;
    float2 a = *(const float2*)(U   + c0);
    float2 b = *(const float2*)(D   + c0);
    float2 e = *(const float2*)(BLt + c0);
    float2 f = *(const float2*)(HWt + c0);
    float2 g = *(const float2*)(HMt + c0);
    u[0]=a.x; u[1]=a.y; d[0]=b.x; d[1]=b.y; bl[0]=e.x; bl[1]=e.y;
    hw[0]=f.x; hw[1]=f.y; hm[0]=g.x; hm[1]=g.y;
  }

  // bin index: count edges < x across the group, clamp
  int cnt = 0;
  float he[C];
#pragma unroll
  for (int i = 0; i < C; ++i) {
    he[i] = __expf(u[i] + d[i]);
    cnt += (bl[i] < xv) ? 1 : 0;
  }
  cnt = grp_sum_i(cnt);
  int bi = min(max(cnt - 1, 0), NB - 2);

  // area and masked partial cdf
  float area = 0.0f, pr = 0.0f;
#pragma unroll
  for (int i = 0; i < C; ++i) {
    float t = he[i] * (hw[i] + hm[i]);
    area += t;
    int j = s * C + i;
    pr += (j <= bi) ? t : 0.0f;
  }
  area = grp_sum(area);
  pr   = grp_sum(pr);

  // boundary values: reload (L1-hot lines) instead of cross-lane extraction
  float inloc = BLt[OFF + bi];
  float hwbi  = HWt[OFF + bi];
  float hl = __expf(U[OFF + bi]     + D[OFF + bi]);
  float hr = __expf(U[OFF + bi + 1] + D[OFF + bi + 1]);

  float part = pr - hl * hwbi;                 // cdf left of bin bi (unnormalized)
  float inw = 2.0f * hwbi;
  float inv_area = __builtin_amdgcn_rcpf(area);
  float alpha = (xv - inloc) * __builtin_amdgcn_rcpf(inw);
  float dh = hr - hl;
  float outv = ((0.5f * dh * alpha + hl) * alpha * inw + part) * inv_area;
  logdet += (__log2f(alpha * dh + hl) - __log2f(area)) * 0.69314718055994531f;
  xv = outv;
}

__global__ void __launch_bounds__(256) spline_kernel(
    const float* __restrict__ x, const int* __restrict__ roi,
    const int* __restrict__ lix, const float* __restrict__ delta,
    const float* __restrict__ hemb,
    const float* __restrict__ wsBL, const float* __restrict__ wsHW,
    const float* __restrict__ wsHM, float* __restrict__ out)
{
  int tid  = (int)(blockIdx.x * blockDim.x + threadIdx.x);
  int wid  = tid >> 6;
  int lane = (int)(threadIdx.x & 63);
  int grp  = lane >> 4;            // 4 points per wave
  int s    = lane & 15;            // 16-lane group, lanes <-> columns
  int pid  = wid * 4 + grp;
  if (pid >= NPOINTS) return;

  float xv = x[pid];               // group-uniform
  int r    = lix[pid];
  int greg = roi[r];
  const float* U   = hemb  + (size_t)greg * SUMH;
  const float* D   = delta + (size_t)pid  * SUMH;
  const float* BLt = wsBL  + (size_t)r    * SUMH;
  const float* HWt = wsHW  + (size_t)r    * SUMH;
  const float* HMt = wsHM  + (size_t)r    * SUMH;

  float logdet = 0.0f;
  level<128,   0, 8>(xv, logdet, U, D, BLt, HWt, HMt, s);
  level< 64, 128, 4>(xv, logdet, U, D, BLt, HWt, HMt, s);
  level< 32, 192, 2>(xv, logdet, U, D, BLt, HWt, HMt, s);

  if (s == 0) {
    out[pid] = xv;
    out[NPOINTS + pid] = logdet;
  }
}

// ---------- launch ----------

extern "C" void kernel_launch(void* const* d_in, const int* in_sizes, int n_in,
                              void* d_out, int out_size, void* d_ws, size_t ws_size,
                              hipStream_t stream) {
  const float* x     = (const float*)d_in[0];
  const int*   roi   = (const int*)  d_in[1];
  const int*   lix   = (const int*)  d_in[2];
  const float* delta = (const float*)d_in[3];
  const float* hemb  = (const float*)d_in[4];
  const float* wemb  = (const float*)d_in[5];

  float* wsBL = (float*)d_ws;                    // [500][224]
  float* wsHW = wsBL + (size_t)NREG * SUMH;      // [500][224]
  float* wsHM = wsHW + (size_t)NREG * SUMH;      // [500][224]

  region_kernel<<<NREG, 64, 0, stream>>>(roi, wemb, wsBL, wsHW, wsHM);
  spline_kernel<<<NPOINTS / 16, 256, 0, stream>>>(x, roi, lix, delta, hemb,
                                                  wsBL, wsHW, wsHM, (float*)d_out);
}